// Round 6
// baseline (228.830 us; speedup 1.0000x reference)
//
#include <hip/hip_runtime.h>

#define D 128
#define EPS 1e-8f
#define E_NUM 10000
#define CAP_E 192    // max nodes per hyperedge (mean 80, max~118, +12.6 sigma)
#define CAP_N 64     // max hyperedges per node (mean 16, max~35, +12 sigma)
#define CHUNK 2048

typedef __attribute__((ext_vector_type(8))) short bf16x8;
typedef __attribute__((ext_vector_type(4))) float f32x4;

__device__ __forceinline__ unsigned bf16rn(float f) {
  unsigned u = __float_as_uint(f);
  return (u + 0x7fffu + ((u >> 16) & 1u)) >> 16;
}
__device__ __forceinline__ unsigned bf16pack(float a, float b) {
  return bf16rn(a) | (bf16rn(b) << 16);
}
__device__ __forceinline__ float lof(unsigned u) { return __uint_as_float(u << 16); }
__device__ __forceinline__ float hif(unsigned u) { return __uint_as_float(u & 0xffff0000u); }

#define ACCQ(u) do { \
    x0 += lof((u).x); y0 += hif((u).x); x1 += lof((u).y); y1 += hif((u).y); \
    x2 += lof((u).z); y2 += hif((u).z); x3 += lof((u).w); y3 += hif((u).w); } while (0)

// ---- K1: blocks [0,LB): direct adjacency-list build; [LB,LB+GB): MFMA gemm.
struct SmemGemm {
  unsigned short Wfrag[2048 * 8];     // 32 KB
  unsigned short cbuf[4][16 * 136];   // 17 KB
};

__global__ __launch_bounds__(256) void k1_gemm_build(
    const float* __restrict__ x, const float* __restrict__ W,
    unsigned* __restrict__ xnb, const int* __restrict__ node_ids,
    const int* __restrict__ edge_ids, int* __restrict__ ecnt,
    int* __restrict__ ncnt, unsigned short* __restrict__ elist,
    unsigned short* __restrict__ nlist, int nnz, int LB, int N) {
  __shared__ SmemGemm g;
  const int t = threadIdx.x;

  if ((int)blockIdx.x < LB) {
    // ---- direct list build: 1 global atomic + 1 small store per side ----
    const int base = (int)blockIdx.x * CHUNK;
    const int lim = min(base + CHUNK, nnz);
    for (int i = base + t; i < lim; i += 256) {
      int e = edge_ids[i];
      int n = node_ids[i];
      int pe = atomicAdd(&ecnt[e], 1);
      if (pe < CAP_E) elist[(size_t)e * CAP_E + pe] = (unsigned short)n;
      int pn = atomicAdd(&ncnt[n], 1);
      if (pn < CAP_N) nlist[(size_t)n * CAP_N + pn] = (unsigned short)e;
    }
    return;
  }

  // ---------------- gemm: 128 rows per block ----------------
  const int wid = t >> 6;
  const int lane = t & 63;
  const int m = lane & 15;
  const int q = lane >> 4;

  #pragma unroll
  for (int i = 0; i < 8; ++i) {
    int c2 = t + i * 256;
    int ctkt = c2 >> 6;
    int l2 = c2 & 63;
    int n = (ctkt >> 2) * 16 + (l2 & 15);
    int k = (ctkt & 3) * 32 + (l2 >> 4) * 8;
    float4 p = *(const float4*)&W[n * 128 + k];
    float4 r = *(const float4*)&W[n * 128 + k + 4];
    uint4 pkk = make_uint4(bf16pack(p.x, p.y), bf16pack(p.z, p.w),
                           bf16pack(r.x, r.y), bf16pack(r.z, r.w));
    *(uint4*)&g.Wfrag[c2 * 8] = pkk;
  }
  __syncthreads();

  const int blockRow = ((int)blockIdx.x - LB) * 128;
  #pragma unroll
  for (int s = 0; s < 2; ++s) {
    const int row0 = blockRow + wid * 32 + s * 16;
    if (row0 >= N) break;   // N % 16 == 0

    bf16x8 a[4];
    #pragma unroll
    for (int kt = 0; kt < 4; ++kt) {
      int k0 = kt * 32 + q * 8;
      float4 p = *(const float4*)&x[(size_t)(row0 + m) * 128 + k0];
      float4 r = *(const float4*)&x[(size_t)(row0 + m) * 128 + k0 + 4];
      union { bf16x8 v; uint4 u; } au;
      au.u = make_uint4(bf16pack(p.x, p.y), bf16pack(p.z, p.w),
                        bf16pack(r.x, r.y), bf16pack(r.z, r.w));
      a[kt] = au.v;
    }

    #pragma unroll
    for (int ct = 0; ct < 8; ++ct) {
      f32x4 acc = {0.f, 0.f, 0.f, 0.f};
      #pragma unroll
      for (int kt = 0; kt < 4; ++kt) {
        bf16x8 b = *(const bf16x8*)&g.Wfrag[((ct * 4 + kt) * 64 + lane) * 8];
        acc = __builtin_amdgcn_mfma_f32_16x16x32_bf16(a[kt], b, acc, 0, 0, 0);
      }
      #pragma unroll
      for (int r = 0; r < 4; ++r)
        g.cbuf[wid][(q * 4 + r) * 136 + ct * 16 + m] =
            (unsigned short)bf16rn(acc[r]);
    }

    #pragma unroll
    for (int pass = 0; pass < 4; ++pass) {
      int chunk = pass * 64 + lane;
      int row = chunk >> 4;
      int cc = chunk & 15;
      uint4 v = *(const uint4*)&g.cbuf[wid][row * 136 + cc * 8];
      *(uint4*)&xnb[(size_t)(row0 + row) * 64 + cc * 4] = v;
    }
  }
}

// ---- per-edge mean of xnb rows: one wave per edge, lists read from global ----
__global__ __launch_bounds__(256) void fuse_edge(
    const int* __restrict__ ecnt, const unsigned short* __restrict__ elist,
    const unsigned* __restrict__ xnb, unsigned* __restrict__ eattr) {
  const int t = threadIdx.x;
  const int wid = t >> 6, lane = t & 63;
  const int h2 = lane >> 4, w = lane & 15;
  const int e = (int)blockIdx.x * 4 + wid;
  if (e >= E_NUM) return;

  const uint4* X4 = (const uint4*)xnb;
  int c = ecnt[e];
  if (c > CAP_E) c = CAP_E;
  const unsigned short* lst = elist + (size_t)e * CAP_E;
  float x0=0,y0=0,x1=0,y1=0,x2=0,y2=0,x3=0,y3=0;
  int m2 = 0;
  uint4 a0, a1, a2, a3;
  if (c >= 16) {
    a0 = X4[(size_t)lst[h2] * 16 + w];
    a1 = X4[(size_t)lst[4 + h2] * 16 + w];
    a2 = X4[(size_t)lst[8 + h2] * 16 + w];
    a3 = X4[(size_t)lst[12 + h2] * 16 + w];
  }
  for (; m2 + 32 <= c; m2 += 16) {
    uint4 b0 = X4[(size_t)lst[m2 + 16 + h2] * 16 + w];
    uint4 b1 = X4[(size_t)lst[m2 + 20 + h2] * 16 + w];
    uint4 b2 = X4[(size_t)lst[m2 + 24 + h2] * 16 + w];
    uint4 b3 = X4[(size_t)lst[m2 + 28 + h2] * 16 + w];
    ACCQ(a0); ACCQ(a1); ACCQ(a2); ACCQ(a3);
    a0 = b0; a1 = b1; a2 = b2; a3 = b3;
  }
  if (m2 + 16 <= c) {
    ACCQ(a0); ACCQ(a1); ACCQ(a2); ACCQ(a3);
    m2 += 16;
  }
  for (; m2 < c; m2 += 4) {
    int ii = m2 + h2;
    int id = lst[ii < c ? ii : m2];
    uint4 u = X4[(size_t)id * 16 + w];
    if (ii < c) ACCQ(u);
  }
  x0 += __shfl_xor(x0, 16); y0 += __shfl_xor(y0, 16);
  x1 += __shfl_xor(x1, 16); y1 += __shfl_xor(y1, 16);
  x2 += __shfl_xor(x2, 16); y2 += __shfl_xor(y2, 16);
  x3 += __shfl_xor(x3, 16); y3 += __shfl_xor(y3, 16);
  x0 += __shfl_xor(x0, 32); y0 += __shfl_xor(y0, 32);
  x1 += __shfl_xor(x1, 32); y1 += __shfl_xor(y1, 32);
  x2 += __shfl_xor(x2, 32); y2 += __shfl_xor(y2, 32);
  x3 += __shfl_xor(x3, 32); y3 += __shfl_xor(y3, 32);
  if (lane < 16) {
    float inv = 1.f / ((float)c + EPS);
    uint4 o = make_uint4(bf16pack(x0 * inv, y0 * inv), bf16pack(x1 * inv, y1 * inv),
                         bf16pack(x2 * inv, y2 * inv), bf16pack(x3 * inv, y3 * inv));
    ((uint4*)eattr)[(size_t)e * 16 + w] = o;
  }
}

// ---- per-node mean of eattr rows + epilogue: one wave per node ----
__global__ __launch_bounds__(256) void fuse_node(
    const int* __restrict__ ncnt, const unsigned short* __restrict__ nlist,
    const unsigned* __restrict__ eattr, const unsigned* __restrict__ xnb,
    const float* __restrict__ bias, float* __restrict__ out, int N) {
  const int t = threadIdx.x;
  const int wid = t >> 6, lane = t & 63;
  const int h2 = lane >> 4, w = lane & 15;
  const int v = (int)blockIdx.x * 4 + wid;
  if (v >= N) return;

  const uint4* E4 = (const uint4*)eattr;
  const float4* B4 = (const float4*)bias;
  float4 bv0 = B4[2 * w], bv1 = B4[2 * w + 1];
  int c = ncnt[v];
  if (c > CAP_N) c = CAP_N;
  const unsigned short* lst = nlist + (size_t)v * CAP_N;
  float x0=0,y0=0,x1=0,y1=0,x2=0,y2=0,x3=0,y3=0;
  int m2 = 0;
  for (; m2 + 16 <= c; m2 += 16) {
    uint4 u0 = E4[(size_t)lst[m2 + h2] * 16 + w];
    uint4 u1 = E4[(size_t)lst[m2 + 4 + h2] * 16 + w];
    uint4 u2 = E4[(size_t)lst[m2 + 8 + h2] * 16 + w];
    uint4 u3 = E4[(size_t)lst[m2 + 12 + h2] * 16 + w];
    ACCQ(u0); ACCQ(u1); ACCQ(u2); ACCQ(u3);
  }
  for (; m2 < c; m2 += 4) {
    int ii = m2 + h2;
    int id = lst[ii < c ? ii : m2];
    uint4 u = E4[(size_t)id * 16 + w];
    if (ii < c) ACCQ(u);
  }
  x0 += __shfl_xor(x0, 16); y0 += __shfl_xor(y0, 16);
  x1 += __shfl_xor(x1, 16); y1 += __shfl_xor(y1, 16);
  x2 += __shfl_xor(x2, 16); y2 += __shfl_xor(y2, 16);
  x3 += __shfl_xor(x3, 16); y3 += __shfl_xor(y3, 16);
  x0 += __shfl_xor(x0, 32); y0 += __shfl_xor(y0, 32);
  x1 += __shfl_xor(x1, 32); y1 += __shfl_xor(y1, 32);
  x2 += __shfl_xor(x2, 32); y2 += __shfl_xor(y2, 32);
  x3 += __shfl_xor(x3, 32); y3 += __shfl_xor(y3, 32);
  if (lane < 16) {
    float inv = 1.f / ((float)c + EPS);
    uint4 xr = ((const uint4*)xnb)[(size_t)v * 16 + w];
    float4 o0 = make_float4(x0 * inv + lof(xr.x) + bv0.x,
                            y0 * inv + hif(xr.x) + bv0.y,
                            x1 * inv + lof(xr.y) + bv0.z,
                            y1 * inv + hif(xr.y) + bv0.w);
    float4 o1 = make_float4(x2 * inv + lof(xr.z) + bv1.x,
                            y2 * inv + hif(xr.z) + bv1.y,
                            x3 * inv + lof(xr.w) + bv1.z,
                            y3 * inv + hif(xr.w) + bv1.w);
    float4* orow = (float4*)(out + (size_t)v * D);
    orow[2 * w] = o0;
    orow[2 * w + 1] = o1;
  }
}

extern "C" void kernel_launch(void* const* d_in, const int* in_sizes, int n_in,
                              void* d_out, int out_size, void* d_ws, size_t ws_size,
                              hipStream_t stream) {
  const float* x = (const float*)d_in[0];
  const int* hidx = (const int*)d_in[1];
  const float* W = (const float*)d_in[2];
  const float* bias = (const float*)d_in[3];

  const int N = in_sizes[0] / D;     // 50000
  const int nnz = in_sizes[1] / 2;   // 800000
  const int* node_ids = hidx;
  const int* edge_ids = hidx + nnz;
  const int LB = (nnz + CHUNK - 1) / CHUNK;    // 391
  const int GB = (N + 127) / 128;              // 391

  // workspace layout (u32 units), total ~25.9 MB
  int* ib = (int*)d_ws;
  int* ecnt = ib;                                   // E_NUM ints
  int* ncnt = ib + 10240;                           // N ints
  unsigned* xnb = (unsigned*)(ib + 61440);          // N*64 u32 (16B-aligned)
  unsigned* eattr = xnb + (size_t)N * 64;           // E_NUM*64 u32
  unsigned short* elist = (unsigned short*)(eattr + (size_t)E_NUM * 64);
  unsigned short* nlist = elist + (size_t)E_NUM * CAP_E;

  (void)hipMemsetAsync(ib, 0, 61440 * sizeof(int), stream);

  k1_gemm_build<<<LB + GB, 256, 0, stream>>>(x, W, xnb, node_ids, edge_ids,
                                             ecnt, ncnt, elist, nlist,
                                             nnz, LB, N);

  fuse_edge<<<(E_NUM + 3) / 4, 256, 0, stream>>>(ecnt, elist, xnb, eattr);

  fuse_node<<<(N + 3) / 4, 256, 0, stream>>>(ncnt, nlist, eattr, xnb, bias,
                                             (float*)d_out, N);
}

// Round 7
// 169.567 us; speedup vs baseline: 1.3495x; 1.3495x over previous
//
#include <hip/hip_runtime.h>

#define D 128
#define EPS 1e-8f
#define E_NUM 10000
#define CAP_E 192    // max nodes per hyperedge (mean 80, +12.6 sigma)
#define CAP_N 64     // max hyperedges per node (mean 16, +12 sigma)
#define CHUNK 2048
#define EB2 625      // edge buckets: e>>4 (16 edges each)
#define NB2 782      // node buckets: n>>6 (64 nodes each)
#define TB 1407      // EB2 + NB2
#define CAPB_E 1536  // slots per edge bucket (Binom mean 1280, +7.2 sigma)
#define CAPB_N 1280  // slots per node bucket (Binom mean 1024, +8 sigma)
#define NODE_BASE (EB2 * CAPB_E)               // 960000
#define STAGE_TOTAL (NODE_BASE + NB2 * CAPB_N) // 1960960

typedef __attribute__((ext_vector_type(8))) short bf16x8;
typedef __attribute__((ext_vector_type(4))) float f32x4;

__device__ __forceinline__ unsigned bf16rn(float f) {
  unsigned u = __float_as_uint(f);
  return (u + 0x7fffu + ((u >> 16) & 1u)) >> 16;
}
__device__ __forceinline__ unsigned bf16pack(float a, float b) {
  return bf16rn(a) | (bf16rn(b) << 16);
}
__device__ __forceinline__ float lof(unsigned u) { return __uint_as_float(u << 16); }
__device__ __forceinline__ float hif(unsigned u) { return __uint_as_float(u & 0xffff0000u); }

#define ACCQ(u) do { \
    x0 += lof((u).x); y0 += hif((u).x); x1 += lof((u).y); y1 += hif((u).y); \
    x2 += lof((u).z); y2 += hif((u).z); x3 += lof((u).w); y3 += hif((u).w); } while (0)

// ---- K1: packed kernel. Blocks [0,C): bucket-scatter; [C, C+GB): MFMA gemm.
struct SmemGemm {
  unsigned short Wfrag[2048 * 8];     // 32 KB
  unsigned short cbuf[4][16 * 136];   // 17 KB
};
struct SmemScat {
  int h[TB];
  int cur[TB];
  int end_[TB];
};

__global__ __launch_bounds__(256) void k1_gemm_scatter(
    const float* __restrict__ x, const float* __restrict__ W,
    unsigned* __restrict__ xnb, const int* __restrict__ node_ids,
    const int* __restrict__ edge_ids, int* __restrict__ gcur,
    unsigned* __restrict__ stage, int nnz, int C, int N) {
  __shared__ union { SmemGemm g; SmemScat s; } sm;
  const int t = threadIdx.x;

  if ((int)blockIdx.x < C) {
    // ---------------- scatter chunk (2048 entries) ----------------
    const int c = blockIdx.x;
    const int base = c * CHUNK;
    const int lim = min(base + CHUNK, nnz);
    unsigned pk[8], rk[8];
    #pragma unroll
    for (int r = 0; r < 8; ++r) {
      int i = base + t + r * 256;
      pk[r] = (i < lim)
          ? (((unsigned)edge_ids[i] << 16) | (unsigned)node_ids[i])
          : 0xffffffffu;
    }
    for (int j = t; j < TB; j += 256) sm.s.h[j] = 0;
    __syncthreads();
    // pass A: histogram; atomic return value IS this entry's rank in bucket
    #pragma unroll
    for (int r = 0; r < 8; ++r) {
      if (pk[r] != 0xffffffffu) {
        unsigned pe = atomicAdd(&sm.s.h[pk[r] >> 20], 1);
        unsigned pn = atomicAdd(&sm.s.h[EB2 + ((pk[r] & 0xffffu) >> 6)], 1);
        rk[r] = pe | (pn << 16);
      } else {
        rk[r] = 0;
      }
    }
    __syncthreads();
    // pass B: one global atomic per nonzero bucket
    for (int j = t; j < TB; j += 256) {
      int hc = sm.s.h[j];
      int rb, cap;
      if (j < EB2) { rb = j * CAPB_E; cap = CAPB_E; }
      else         { rb = NODE_BASE + (j - EB2) * CAPB_N; cap = CAPB_N; }
      int off = hc ? atomicAdd(&gcur[j], hc) : 0;
      sm.s.cur[j] = rb + off;
      sm.s.end_[j] = rb + cap;
    }
    __syncthreads();
    // pass C: atomic-free scatter using saved ranks (coalesced-ish u32 stores)
    #pragma unroll
    for (int r = 0; r < 8; ++r) {
      if (pk[r] != 0xffffffffu) {
        int be = pk[r] >> 20;
        int bn = EB2 + ((pk[r] & 0xffffu) >> 6);
        int pe = sm.s.cur[be] + (int)(rk[r] & 0xffffu);
        if (pe < sm.s.end_[be]) stage[pe] = pk[r];
        int pn = sm.s.cur[bn] + (int)(rk[r] >> 16);
        if (pn < sm.s.end_[bn]) stage[pn] = (pk[r] << 16) | (pk[r] >> 16);
      }
    }
    return;
  }

  // ---------------- gemm: 128 rows per block ----------------
  const int wid = t >> 6;
  const int lane = t & 63;
  const int m = lane & 15;
  const int q = lane >> 4;

  #pragma unroll
  for (int i = 0; i < 8; ++i) {
    int c2 = t + i * 256;
    int ctkt = c2 >> 6;
    int l2 = c2 & 63;
    int n = (ctkt >> 2) * 16 + (l2 & 15);
    int k = (ctkt & 3) * 32 + (l2 >> 4) * 8;
    float4 p = *(const float4*)&W[n * 128 + k];
    float4 r = *(const float4*)&W[n * 128 + k + 4];
    uint4 pkk = make_uint4(bf16pack(p.x, p.y), bf16pack(p.z, p.w),
                           bf16pack(r.x, r.y), bf16pack(r.z, r.w));
    *(uint4*)&sm.g.Wfrag[c2 * 8] = pkk;
  }
  __syncthreads();

  const int blockRow = ((int)blockIdx.x - C) * 128;
  #pragma unroll
  for (int s = 0; s < 2; ++s) {
    const int row0 = blockRow + wid * 32 + s * 16;
    if (row0 >= N) break;   // N % 16 == 0

    bf16x8 a[4];
    #pragma unroll
    for (int kt = 0; kt < 4; ++kt) {
      int k0 = kt * 32 + q * 8;
      float4 p = *(const float4*)&x[(size_t)(row0 + m) * 128 + k0];
      float4 r = *(const float4*)&x[(size_t)(row0 + m) * 128 + k0 + 4];
      union { bf16x8 v; uint4 u; } au;
      au.u = make_uint4(bf16pack(p.x, p.y), bf16pack(p.z, p.w),
                        bf16pack(r.x, r.y), bf16pack(r.z, r.w));
      a[kt] = au.v;
    }

    #pragma unroll
    for (int ct = 0; ct < 8; ++ct) {
      f32x4 acc = {0.f, 0.f, 0.f, 0.f};
      #pragma unroll
      for (int kt = 0; kt < 4; ++kt) {
        bf16x8 b = *(const bf16x8*)&sm.g.Wfrag[((ct * 4 + kt) * 64 + lane) * 8];
        acc = __builtin_amdgcn_mfma_f32_16x16x32_bf16(a[kt], b, acc, 0, 0, 0);
      }
      #pragma unroll
      for (int r = 0; r < 4; ++r)
        sm.g.cbuf[wid][(q * 4 + r) * 136 + ct * 16 + m] =
            (unsigned short)bf16rn(acc[r]);
    }

    #pragma unroll
    for (int pass = 0; pass < 4; ++pass) {
      int chunk = pass * 64 + lane;
      int row = chunk >> 4;
      int cc = chunk & 15;
      uint4 v = *(const uint4*)&sm.g.cbuf[wid][row * 136 + cc * 8];
      *(uint4*)&xnb[(size_t)(row0 + row) * 64 + cc * 4] = v;
    }
  }
}

// ---- listify: convert each 16-edge bucket into 16 contiguous per-edge u16
//      lists, written back IN PLACE over the bucket (coalesced u32 stores).
__global__ __launch_bounds__(256) void listify_edge(
    const int* __restrict__ gcur, unsigned* __restrict__ stage,
    int* __restrict__ ecnt) {
  __shared__ unsigned short l16[16][CAP_E];   // 6 KB, 16*192 u16 = 1536 u32
  __shared__ int lc[16];
  const int b = blockIdx.x, t = threadIdx.x;
  if (t < 16) lc[t] = 0;
  __syncthreads();
  int total = gcur[b];
  if (total > CAPB_E) total = CAPB_E;
  unsigned* seg = stage + (size_t)b * CAPB_E;
  #pragma unroll
  for (int r = 0; r < 6; ++r) {              // 6*256 = 1536 >= CAPB_E
    int i = t + r * 256;
    if (i < total) {
      unsigned pkv = seg[i];
      int e = (pkv >> 16) & 15;
      int p = atomicAdd(&lc[e], 1);
      if (p < CAP_E) l16[e][p] = (unsigned short)(pkv & 0xffffu);
    }
  }
  __syncthreads();
  if (t < 16) ecnt[b * 16 + t] = min(lc[t], CAP_E);
  const unsigned* src = (const unsigned*)l16;
  for (int i = t; i < 1536; i += 256) seg[i] = src[i];
}

// ---- per-edge mean of xnb rows: one wave per edge, direct list read ----
__global__ __launch_bounds__(256) void fuse_edge(
    const int* __restrict__ ecnt, const unsigned* __restrict__ stage,
    const unsigned* __restrict__ xnb, unsigned* __restrict__ eattr) {
  const int t = threadIdx.x;
  const int wid = t >> 6, lane = t & 63;
  const int h2 = lane >> 4, w = lane & 15;
  const int e = (int)blockIdx.x * 4 + wid;   // grid 2500 -> e < 10000
  const uint4* X4 = (const uint4*)xnb;
  int c = ecnt[e];
  const unsigned short* lst =
      (const unsigned short*)(stage + (size_t)(e >> 4) * CAPB_E) +
      (e & 15) * CAP_E;
  float x0=0,y0=0,x1=0,y1=0,x2=0,y2=0,x3=0,y3=0;
  int m2 = 0;
  uint4 a0, a1, a2, a3;
  if (c >= 16) {
    a0 = X4[(size_t)lst[h2] * 16 + w];
    a1 = X4[(size_t)lst[4 + h2] * 16 + w];
    a2 = X4[(size_t)lst[8 + h2] * 16 + w];
    a3 = X4[(size_t)lst[12 + h2] * 16 + w];
  }
  for (; m2 + 32 <= c; m2 += 16) {
    uint4 b0 = X4[(size_t)lst[m2 + 16 + h2] * 16 + w];
    uint4 b1 = X4[(size_t)lst[m2 + 20 + h2] * 16 + w];
    uint4 b2 = X4[(size_t)lst[m2 + 24 + h2] * 16 + w];
    uint4 b3 = X4[(size_t)lst[m2 + 28 + h2] * 16 + w];
    ACCQ(a0); ACCQ(a1); ACCQ(a2); ACCQ(a3);
    a0 = b0; a1 = b1; a2 = b2; a3 = b3;
  }
  if (m2 + 16 <= c) {
    ACCQ(a0); ACCQ(a1); ACCQ(a2); ACCQ(a3);
    m2 += 16;
  }
  for (; m2 < c; m2 += 4) {
    int ii = m2 + h2;
    int id = lst[ii < c ? ii : m2];
    uint4 u = X4[(size_t)id * 16 + w];
    if (ii < c) ACCQ(u);
  }
  x0 += __shfl_xor(x0, 16); y0 += __shfl_xor(y0, 16);
  x1 += __shfl_xor(x1, 16); y1 += __shfl_xor(y1, 16);
  x2 += __shfl_xor(x2, 16); y2 += __shfl_xor(y2, 16);
  x3 += __shfl_xor(x3, 16); y3 += __shfl_xor(y3, 16);
  x0 += __shfl_xor(x0, 32); y0 += __shfl_xor(y0, 32);
  x1 += __shfl_xor(x1, 32); y1 += __shfl_xor(y1, 32);
  x2 += __shfl_xor(x2, 32); y2 += __shfl_xor(y2, 32);
  x3 += __shfl_xor(x3, 32); y3 += __shfl_xor(y3, 32);
  if (lane < 16) {
    float inv = 1.f / ((float)c + EPS);
    uint4 o = make_uint4(bf16pack(x0 * inv, y0 * inv), bf16pack(x1 * inv, y1 * inv),
                         bf16pack(x2 * inv, y2 * inv), bf16pack(x3 * inv, y3 * inv));
    ((uint4*)eattr)[(size_t)e * 16 + w] = o;
  }
}

// ---- fused: build 64-node lists in LDS, uint4 gather eattr, epilogue ----
__global__ __launch_bounds__(512) void fuse_node(
    const unsigned* __restrict__ stage, const int* __restrict__ gcur,
    const unsigned* __restrict__ eattr, const unsigned* __restrict__ xnb,
    const float* __restrict__ bias, float* __restrict__ out, int N) {
  __shared__ __align__(16) unsigned short lists[64 * CAP_N];  // 8 KB
  __shared__ int lc[64];
  int b = blockIdx.x, t = threadIdx.x;
  if (t < 64) lc[t] = 0;
  __syncthreads();
  int total = gcur[EB2 + b];
  if (total > CAPB_N) total = CAPB_N;
  const unsigned* seg = stage + NODE_BASE + (size_t)b * CAPB_N;
  for (int i = t; i < total; i += 512) {
    unsigned pkv = seg[i];
    int n = pkv >> 16;
    int p = atomicAdd(&lc[n & 63], 1);
    if (p < CAP_N) lists[(n & 63) * CAP_N + p] = (unsigned short)(pkv & 0xffffu);
  }
  __syncthreads();

  const int wid = t >> 6, lane = t & 63;
  const int h2 = lane >> 4, w = lane & 15;
  const uint4* E4 = (const uint4*)eattr;
  const float4* B4 = (const float4*)bias;
  float4 bv0 = B4[2 * w], bv1 = B4[2 * w + 1];
  #pragma unroll
  for (int rep = 0; rep < 8; ++rep) {
    int j = wid + rep * 8;
    int v = (b << 6) + j;
    if (v >= N) continue;
    int c = lc[j];
    if (c > CAP_N) c = CAP_N;
    const unsigned short* lst = &lists[j * CAP_N];
    float x0=0,y0=0,x1=0,y1=0,x2=0,y2=0,x3=0,y3=0;
    int m2 = 0;
    for (; m2 + 16 <= c; m2 += 16) {
      uint4 u0 = E4[(size_t)lst[m2 + h2] * 16 + w];
      uint4 u1 = E4[(size_t)lst[m2 + 4 + h2] * 16 + w];
      uint4 u2 = E4[(size_t)lst[m2 + 8 + h2] * 16 + w];
      uint4 u3 = E4[(size_t)lst[m2 + 12 + h2] * 16 + w];
      ACCQ(u0); ACCQ(u1); ACCQ(u2); ACCQ(u3);
    }
    for (; m2 < c; m2 += 4) {
      int ii = m2 + h2;
      int id = lst[ii < c ? ii : m2];
      uint4 u = E4[(size_t)id * 16 + w];
      if (ii < c) ACCQ(u);
    }
    x0 += __shfl_xor(x0, 16); y0 += __shfl_xor(y0, 16);
    x1 += __shfl_xor(x1, 16); y1 += __shfl_xor(y1, 16);
    x2 += __shfl_xor(x2, 16); y2 += __shfl_xor(y2, 16);
    x3 += __shfl_xor(x3, 16); y3 += __shfl_xor(y3, 16);
    x0 += __shfl_xor(x0, 32); y0 += __shfl_xor(y0, 32);
    x1 += __shfl_xor(x1, 32); y1 += __shfl_xor(y1, 32);
    x2 += __shfl_xor(x2, 32); y2 += __shfl_xor(y2, 32);
    x3 += __shfl_xor(x3, 32); y3 += __shfl_xor(y3, 32);
    if (lane < 16) {
      float inv = 1.f / ((float)c + EPS);
      uint4 xr = ((const uint4*)xnb)[(size_t)v * 16 + w];
      float4 o0 = make_float4(x0 * inv + lof(xr.x) + bv0.x,
                              y0 * inv + hif(xr.x) + bv0.y,
                              x1 * inv + lof(xr.y) + bv0.z,
                              y1 * inv + hif(xr.y) + bv0.w);
      float4 o1 = make_float4(x2 * inv + lof(xr.z) + bv1.x,
                              y2 * inv + hif(xr.z) + bv1.y,
                              x3 * inv + lof(xr.w) + bv1.z,
                              y3 * inv + hif(xr.w) + bv1.w);
      float4* orow = (float4*)(out + (size_t)v * D);
      orow[2 * w] = o0;
      orow[2 * w + 1] = o1;
    }
  }
}

extern "C" void kernel_launch(void* const* d_in, const int* in_sizes, int n_in,
                              void* d_out, int out_size, void* d_ws, size_t ws_size,
                              hipStream_t stream) {
  const float* x = (const float*)d_in[0];
  const int* hidx = (const int*)d_in[1];
  const float* W = (const float*)d_in[2];
  const float* bias = (const float*)d_in[3];

  const int N = in_sizes[0] / D;     // 50000
  const int nnz = in_sizes[1] / 2;   // 800000
  const int* node_ids = hidx;
  const int* edge_ids = hidx + nnz;
  const int C = (nnz + CHUNK - 1) / CHUNK;     // 391
  const int GB = (N + 127) / 128;              // 391

  // workspace (u32 units): gcur@0, ecnt@2048, stage@16384, xnb, eattr (~23.3MB)
  int* ib = (int*)d_ws;
  int* gcur = ib;                                        // TB ints (zeroed)
  int* ecnt = ib + 2048;                                 // E_NUM ints
  unsigned* stage = (unsigned*)(ib + 16384);             // STAGE_TOTAL u32
  unsigned* xnb = stage + STAGE_TOTAL;                   // N*64 u32
  unsigned* eattr = xnb + (size_t)N * 64;                // E_NUM*64 u32

  (void)hipMemsetAsync(gcur, 0, TB * sizeof(int), stream);

  k1_gemm_scatter<<<C + GB, 256, 0, stream>>>(x, W, xnb, node_ids, edge_ids,
                                              gcur, stage, nnz, C, N);

  listify_edge<<<EB2, 256, 0, stream>>>(gcur, stage, ecnt);

  fuse_edge<<<(E_NUM + 3) / 4, 256, 0, stream>>>(ecnt, stage, xnb, eattr);

  fuse_node<<<NB2, 512, 0, stream>>>(stage, gcur, eattr, xnb, bias,
                                     (float*)d_out, N);
}

// Round 8
// 162.783 us; speedup vs baseline: 1.4057x; 1.0417x over previous
//
#include <hip/hip_runtime.h>

#define D 128
#define EPS 1e-8f
#define E_NUM 10000
#define CAP_E 192    // max nodes per hyperedge (mean 80, max~125)
#define CAP_N 64     // max hyperedges per node (mean 16, max~34)
#define CHUNK 2048
#define EB2 625      // edge coarse buckets: e>>4 (16 edges each)
#define NB2 782      // node coarse buckets: n>>6 (64 nodes each)
#define TB 1407      // EB2 + NB2
#define CAPB_E 1536  // slots per edge bucket (Binom mean 1280, +7.2 sigma)
#define CAPB_N 1280  // slots per node bucket (Binom mean 1024, +8 sigma)
#define NODE_BASE (EB2 * CAPB_E)               // 960000
#define STAGE_TOTAL (NODE_BASE + NB2 * CAPB_N) // 1960960

typedef __attribute__((ext_vector_type(8))) short bf16x8;
typedef __attribute__((ext_vector_type(4))) float f32x4;

__device__ __forceinline__ unsigned bf16rn(float f) {
  unsigned u = __float_as_uint(f);
  return (u + 0x7fffu + ((u >> 16) & 1u)) >> 16;
}
__device__ __forceinline__ unsigned bf16pack(float a, float b) {
  return bf16rn(a) | (bf16rn(b) << 16);
}
__device__ __forceinline__ float lof(unsigned u) { return __uint_as_float(u << 16); }
__device__ __forceinline__ float hif(unsigned u) { return __uint_as_float(u & 0xffff0000u); }

#define ACCQ(u) do { \
    x0 += lof((u).x); y0 += hif((u).x); x1 += lof((u).y); y1 += hif((u).y); \
    x2 += lof((u).z); y2 += hif((u).z); x3 += lof((u).w); y3 += hif((u).w); } while (0)

// ---- K1: packed kernel. Blocks [0,C): bucket-scatter; [C, C+GB): MFMA gemm.
struct SmemGemm {
  unsigned short Wfrag[2048 * 8];     // 32 KB
  unsigned short cbuf[4][16 * 136];   // 17 KB
};
struct SmemScat {
  int h[TB];
  int cur[TB];
  int end_[TB];
};

__global__ __launch_bounds__(256) void k1_gemm_scatter(
    const float* __restrict__ x, const float* __restrict__ W,
    unsigned* __restrict__ xnb, const int* __restrict__ node_ids,
    const int* __restrict__ edge_ids, int* __restrict__ gcur,
    unsigned* __restrict__ stage, int nnz, int C, int N) {
  __shared__ union { SmemGemm g; SmemScat s; } sm;
  const int t = threadIdx.x;

  if ((int)blockIdx.x < C) {
    // ---------------- scatter chunk (2048 entries) ----------------
    const int c = blockIdx.x;
    const int base = c * CHUNK;
    const int lim = min(base + CHUNK, nnz);
    unsigned pk[8], rk[8];
    #pragma unroll
    for (int r = 0; r < 8; ++r) {
      int i = base + t + r * 256;
      pk[r] = (i < lim)
          ? (((unsigned)edge_ids[i] << 16) | (unsigned)node_ids[i])
          : 0xffffffffu;
    }
    for (int j = t; j < TB; j += 256) sm.s.h[j] = 0;
    __syncthreads();
    // pass A: histogram; atomic return value IS this entry's rank in bucket
    #pragma unroll
    for (int r = 0; r < 8; ++r) {
      if (pk[r] != 0xffffffffu) {
        unsigned pe = atomicAdd(&sm.s.h[pk[r] >> 20], 1);
        unsigned pn = atomicAdd(&sm.s.h[EB2 + ((pk[r] & 0xffffu) >> 6)], 1);
        rk[r] = pe | (pn << 16);
      } else {
        rk[r] = 0;
      }
    }
    __syncthreads();
    // pass B: one global atomic per nonzero bucket
    for (int j = t; j < TB; j += 256) {
      int hc = sm.s.h[j];
      int rb, cap;
      if (j < EB2) { rb = j * CAPB_E; cap = CAPB_E; }
      else         { rb = NODE_BASE + (j - EB2) * CAPB_N; cap = CAPB_N; }
      int off = hc ? atomicAdd(&gcur[j], hc) : 0;
      sm.s.cur[j] = rb + off;
      sm.s.end_[j] = rb + cap;
    }
    __syncthreads();
    // pass C: atomic-free scatter using saved ranks
    #pragma unroll
    for (int r = 0; r < 8; ++r) {
      if (pk[r] != 0xffffffffu) {
        int be = pk[r] >> 20;
        int bn = EB2 + ((pk[r] & 0xffffu) >> 6);
        int pe = sm.s.cur[be] + (int)(rk[r] & 0xffffu);
        if (pe < sm.s.end_[be]) stage[pe] = pk[r];
        int pn = sm.s.cur[bn] + (int)(rk[r] >> 16);
        if (pn < sm.s.end_[bn]) stage[pn] = (pk[r] << 16) | (pk[r] >> 16);
      }
    }
    return;
  }

  // ---------------- gemm: 128 rows per block ----------------
  const int wid = t >> 6;
  const int lane = t & 63;
  const int m = lane & 15;
  const int q = lane >> 4;

  #pragma unroll
  for (int i = 0; i < 8; ++i) {
    int c2 = t + i * 256;
    int ctkt = c2 >> 6;
    int l2 = c2 & 63;
    int n = (ctkt >> 2) * 16 + (l2 & 15);
    int k = (ctkt & 3) * 32 + (l2 >> 4) * 8;
    float4 p = *(const float4*)&W[n * 128 + k];
    float4 r = *(const float4*)&W[n * 128 + k + 4];
    uint4 pkk = make_uint4(bf16pack(p.x, p.y), bf16pack(p.z, p.w),
                           bf16pack(r.x, r.y), bf16pack(r.z, r.w));
    *(uint4*)&sm.g.Wfrag[c2 * 8] = pkk;
  }
  __syncthreads();

  const int blockRow = ((int)blockIdx.x - C) * 128;
  #pragma unroll
  for (int s = 0; s < 2; ++s) {
    const int row0 = blockRow + wid * 32 + s * 16;
    if (row0 >= N) break;   // N % 16 == 0

    bf16x8 a[4];
    #pragma unroll
    for (int kt = 0; kt < 4; ++kt) {
      int k0 = kt * 32 + q * 8;
      float4 p = *(const float4*)&x[(size_t)(row0 + m) * 128 + k0];
      float4 r = *(const float4*)&x[(size_t)(row0 + m) * 128 + k0 + 4];
      union { bf16x8 v; uint4 u; } au;
      au.u = make_uint4(bf16pack(p.x, p.y), bf16pack(p.z, p.w),
                        bf16pack(r.x, r.y), bf16pack(r.z, r.w));
      a[kt] = au.v;
    }

    #pragma unroll
    for (int ct = 0; ct < 8; ++ct) {
      f32x4 acc = {0.f, 0.f, 0.f, 0.f};
      #pragma unroll
      for (int kt = 0; kt < 4; ++kt) {
        bf16x8 b = *(const bf16x8*)&sm.g.Wfrag[((ct * 4 + kt) * 64 + lane) * 8];
        acc = __builtin_amdgcn_mfma_f32_16x16x32_bf16(a[kt], b, acc, 0, 0, 0);
      }
      #pragma unroll
      for (int r = 0; r < 4; ++r)
        sm.g.cbuf[wid][(q * 4 + r) * 136 + ct * 16 + m] =
            (unsigned short)bf16rn(acc[r]);
    }

    #pragma unroll
    for (int pass = 0; pass < 4; ++pass) {
      int chunk = pass * 64 + lane;
      int row = chunk >> 4;
      int cc = chunk & 15;
      uint4 v = *(const uint4*)&sm.g.cbuf[wid][row * 136 + cc * 8];
      *(uint4*)&xnb[(size_t)(row0 + row) * 64 + cc * 4] = v;
    }
  }
}

// ---- fused: build 16-edge lists in LDS, uint4 gather-mean (4 rows/instr) ----
__global__ __launch_bounds__(512) void fuse_edge(
    const unsigned* __restrict__ stage, const int* __restrict__ gcur,
    const unsigned* __restrict__ xnb, unsigned* __restrict__ eattr) {
  __shared__ __align__(16) unsigned short lists[16 * CAP_E];  // 6 KB
  __shared__ int lc[16];
  int b = blockIdx.x, t = threadIdx.x;
  if (t < 16) lc[t] = 0;
  __syncthreads();
  int total = gcur[b];
  if (total > CAPB_E) total = CAPB_E;
  const unsigned* seg = stage + (size_t)b * CAPB_E;
  for (int i = t; i < total; i += 512) {
    unsigned pkv = seg[i];
    int e = pkv >> 16;
    int p = atomicAdd(&lc[e & 15], 1);
    if (p < CAP_E) lists[(e & 15) * CAP_E + p] = (unsigned short)(pkv & 0xffffu);
  }
  __syncthreads();

  const int wid = t >> 6, lane = t & 63;
  const int h2 = lane >> 4, w = lane & 15;
  const uint4* X4 = (const uint4*)xnb;
  #pragma unroll
  for (int rep = 0; rep < 2; ++rep) {
    int j = wid + rep * 8;
    int e = (b << 4) + j;
    int c = lc[j];
    if (c > CAP_E) c = CAP_E;
    const unsigned short* lst = &lists[j * CAP_E];
    float x0=0,y0=0,x1=0,y1=0,x2=0,y2=0,x3=0,y3=0;
    int m2 = 0;
    #pragma unroll 2
    for (; m2 + 16 <= c; m2 += 16) {
      int i0 = lst[m2 + h2],     i1 = lst[m2 + 4 + h2],
          i2 = lst[m2 + 8 + h2], i3 = lst[m2 + 12 + h2];
      uint4 u0 = X4[(size_t)i0 * 16 + w];
      uint4 u1 = X4[(size_t)i1 * 16 + w];
      uint4 u2 = X4[(size_t)i2 * 16 + w];
      uint4 u3 = X4[(size_t)i3 * 16 + w];
      ACCQ(u0); ACCQ(u1); ACCQ(u2); ACCQ(u3);
    }
    for (; m2 < c; m2 += 4) {
      int ii = m2 + h2;
      int id = lst[ii < c ? ii : m2];
      uint4 u = X4[(size_t)id * 16 + w];
      if (ii < c) ACCQ(u);
    }
    x0 += __shfl_xor(x0, 16); y0 += __shfl_xor(y0, 16);
    x1 += __shfl_xor(x1, 16); y1 += __shfl_xor(y1, 16);
    x2 += __shfl_xor(x2, 16); y2 += __shfl_xor(y2, 16);
    x3 += __shfl_xor(x3, 16); y3 += __shfl_xor(y3, 16);
    x0 += __shfl_xor(x0, 32); y0 += __shfl_xor(y0, 32);
    x1 += __shfl_xor(x1, 32); y1 += __shfl_xor(y1, 32);
    x2 += __shfl_xor(x2, 32); y2 += __shfl_xor(y2, 32);
    x3 += __shfl_xor(x3, 32); y3 += __shfl_xor(y3, 32);
    if (lane < 16) {
      float inv = 1.f / ((float)c + EPS);
      uint4 o = make_uint4(bf16pack(x0 * inv, y0 * inv), bf16pack(x1 * inv, y1 * inv),
                           bf16pack(x2 * inv, y2 * inv), bf16pack(x3 * inv, y3 * inv));
      ((uint4*)eattr)[(size_t)e * 16 + w] = o;
    }
  }
}

// ---- fused: build 64-node lists in LDS, uint4 gather eattr, epilogue ----
__global__ __launch_bounds__(512) void fuse_node(
    const unsigned* __restrict__ stage, const int* __restrict__ gcur,
    const unsigned* __restrict__ eattr, const unsigned* __restrict__ xnb,
    const float* __restrict__ bias, float* __restrict__ out, int N) {
  __shared__ __align__(16) unsigned short lists[64 * CAP_N];  // 8 KB
  __shared__ int lc[64];
  int b = blockIdx.x, t = threadIdx.x;
  if (t < 64) lc[t] = 0;
  __syncthreads();
  int total = gcur[EB2 + b];
  if (total > CAPB_N) total = CAPB_N;
  const unsigned* seg = stage + NODE_BASE + (size_t)b * CAPB_N;
  for (int i = t; i < total; i += 512) {
    unsigned pkv = seg[i];
    int n = pkv >> 16;
    int p = atomicAdd(&lc[n & 63], 1);
    if (p < CAP_N) lists[(n & 63) * CAP_N + p] = (unsigned short)(pkv & 0xffffu);
  }
  __syncthreads();

  const int wid = t >> 6, lane = t & 63;
  const int h2 = lane >> 4, w = lane & 15;
  const uint4* E4 = (const uint4*)eattr;
  const uint4* X4n = (const uint4*)xnb;
  const float4* B4 = (const float4*)bias;
  float4 bv0 = B4[2 * w], bv1 = B4[2 * w + 1];
  #pragma unroll
  for (int rep = 0; rep < 8; ++rep) {
    int j = wid + rep * 8;
    int v = (b << 6) + j;
    if (v >= N) continue;
    int c = lc[j];
    if (c > CAP_N) c = CAP_N;
    const unsigned short* lst = &lists[j * CAP_N];
    // T14: issue the xnb residual-row read EARLY so its latency hides
    // under the eattr gather chain (consumed only in the epilogue).
    uint4 xr = X4n[(size_t)v * 16 + w];
    float x0=0,y0=0,x1=0,y1=0,x2=0,y2=0,x3=0,y3=0;
    int m2 = 0;
    for (; m2 + 16 <= c; m2 += 16) {
      int i0 = lst[m2 + h2],     i1 = lst[m2 + 4 + h2],
          i2 = lst[m2 + 8 + h2], i3 = lst[m2 + 12 + h2];
      uint4 u0 = E4[(size_t)i0 * 16 + w];
      uint4 u1 = E4[(size_t)i1 * 16 + w];
      uint4 u2 = E4[(size_t)i2 * 16 + w];
      uint4 u3 = E4[(size_t)i3 * 16 + w];
      ACCQ(u0); ACCQ(u1); ACCQ(u2); ACCQ(u3);
    }
    for (; m2 < c; m2 += 4) {
      int ii = m2 + h2;
      int id = lst[ii < c ? ii : m2];
      uint4 u = E4[(size_t)id * 16 + w];
      if (ii < c) ACCQ(u);
    }
    x0 += __shfl_xor(x0, 16); y0 += __shfl_xor(y0, 16);
    x1 += __shfl_xor(x1, 16); y1 += __shfl_xor(y1, 16);
    x2 += __shfl_xor(x2, 16); y2 += __shfl_xor(y2, 16);
    x3 += __shfl_xor(x3, 16); y3 += __shfl_xor(y3, 16);
    x0 += __shfl_xor(x0, 32); y0 += __shfl_xor(y0, 32);
    x1 += __shfl_xor(x1, 32); y1 += __shfl_xor(y1, 32);
    x2 += __shfl_xor(x2, 32); y2 += __shfl_xor(y2, 32);
    x3 += __shfl_xor(x3, 32); y3 += __shfl_xor(y3, 32);
    if (lane < 16) {
      float inv = 1.f / ((float)c + EPS);
      float4 o0 = make_float4(x0 * inv + lof(xr.x) + bv0.x,
                              y0 * inv + hif(xr.x) + bv0.y,
                              x1 * inv + lof(xr.y) + bv0.z,
                              y1 * inv + hif(xr.y) + bv0.w);
      float4 o1 = make_float4(x2 * inv + lof(xr.z) + bv1.x,
                              y2 * inv + hif(xr.z) + bv1.y,
                              x3 * inv + lof(xr.w) + bv1.z,
                              y3 * inv + hif(xr.w) + bv1.w);
      float4* orow = (float4*)(out + (size_t)v * D);
      orow[2 * w] = o0;
      orow[2 * w + 1] = o1;
    }
  }
}

extern "C" void kernel_launch(void* const* d_in, const int* in_sizes, int n_in,
                              void* d_out, int out_size, void* d_ws, size_t ws_size,
                              hipStream_t stream) {
  const float* x = (const float*)d_in[0];
  const int* hidx = (const int*)d_in[1];
  const float* W = (const float*)d_in[2];
  const float* bias = (const float*)d_in[3];

  const int N = in_sizes[0] / D;     // 50000
  const int nnz = in_sizes[1] / 2;   // 800000
  const int* node_ids = hidx;
  const int* edge_ids = hidx + nnz;
  const int C = (nnz + CHUNK - 1) / CHUNK;     // 391
  const int GB = (N + 127) / 128;              // 391

  // workspace (u32 units), total ~23.2 MB
  int* ib = (int*)d_ws;
  int* gcur = ib;                                        // TB ints (zeroed)
  unsigned* stage = (unsigned*)(ib + 2048);              // STAGE_TOTAL u32
  unsigned* xnb = (unsigned*)(ib + 2048 + STAGE_TOTAL);  // N*64 u32
  unsigned* eattr = xnb + (size_t)N * 64;                // E_NUM*64 u32

  (void)hipMemsetAsync(gcur, 0, TB * sizeof(int), stream);

  k1_gemm_scatter<<<C + GB, 256, 0, stream>>>(x, W, xnb, node_ids, edge_ids,
                                              gcur, stage, nnz, C, N);

  fuse_edge<<<EB2, 512, 0, stream>>>(stage, gcur, xnb, eattr);

  fuse_node<<<NB2, 512, 0, stream>>>(stage, gcur, eattr, xnb, bias,
                                     (float*)d_out, N);
}